// Round 1
// baseline (953.221 us; speedup 1.0000x reference)
//
#include <hip/hip_runtime.h>
#include <hip/hip_bf16.h>

#define N_NODES 100000
#define N_EDGES 1600000
#define IN_F 128
#define OUT_F 64
#define EMB 64
#define ATT 32
#define MAX_R 5
#define ALPHA 0.2f

// ---------------- K1: h = inputs @ W  (+ s_src, s_dst epilogue) ----------------
// block = 256 = 4 waves; wave w handles row r = blk*4+w; lane = output column.
__global__ __launch_bounds__(256) void k_gemm(const float* __restrict__ inp,
                                              const float* __restrict__ W,
                                              const float* __restrict__ a,
                                              float* __restrict__ h,
                                              float* __restrict__ s_src,
                                              float* __restrict__ s_dst) {
    __shared__ float Wl[IN_F * OUT_F];      // 32 KB
    __shared__ float inl[4][IN_F];          // 2 KB

    // cooperative W load, float4-vectorized, coalesced
    float4* Wl4 = (float4*)Wl;
    const float4* W4 = (const float4*)W;
#pragma unroll
    for (int i = 0; i < (IN_F * OUT_F / 4) / 256; ++i)
        Wl4[threadIdx.x + i * 256] = W4[threadIdx.x + i * 256];

    const int w = threadIdx.x >> 6, lane = threadIdx.x & 63;
    const int r = blockIdx.x * 4 + w;       // grid sized so r < N_NODES always
    inl[w][lane]      = inp[(size_t)r * IN_F + lane];
    inl[w][64 + lane] = inp[(size_t)r * IN_F + 64 + lane];
    __syncthreads();

    float acc = 0.f;
#pragma unroll
    for (int k = 0; k < IN_F; ++k)
        acc = fmaf(inl[w][k], Wl[k * OUT_F + lane], acc);  // broadcast + 2-way (free)

    h[(size_t)r * OUT_F + lane] = acc;

    // s_src[r] = h[r]·a[0:64], s_dst[r] = h[r]·a[64:128]
    float ps = acc * a[lane];
    float pd = acc * a[64 + lane];
#pragma unroll
    for (int m = 32; m; m >>= 1) {
        ps += __shfl_xor(ps, m);
        pd += __shfl_xor(pd, m);
    }
    if (lane == 0) { s_src[r] = ps; s_dst[r] = pd; }
}

// ---------------- K1b: v_re = re_W @ a_re (64), v_ra = ra_W @ a_ra (5) ----------------
__global__ void k_vre(const float* __restrict__ re_W, const float* __restrict__ ra_W,
                      const float* __restrict__ a, float* __restrict__ v_re,
                      float* __restrict__ v_ra) {
    int t = threadIdx.x;
    if (t < EMB) {
        float s = 0.f;
        for (int j = 0; j < ATT; ++j) s = fmaf(re_W[t * ATT + j], a[2 * OUT_F + j], s);
        v_re[t] = s;
    } else if (t < EMB + MAX_R) {
        int m = t - EMB;
        float s = 0.f;
        for (int j = 0; j < ATT; ++j) s = fmaf(ra_W[m * ATT + j], a[2 * OUT_F + ATT + j], s);
        v_ra[m] = s;
    }
}

// ---------------- K2: per-edge score -> edge_e, histogram counts[src] ----------------
// 16 lanes per edge; review row (64 floats) read as 16 x float4, fully coalesced.
__global__ __launch_bounds__(256) void k_edge(const int* __restrict__ edge,
                                              const float* __restrict__ review,
                                              const float* __restrict__ rating,
                                              const float* __restrict__ s_src,
                                              const float* __restrict__ s_dst,
                                              const float* __restrict__ v_re,
                                              const float* __restrict__ v_ra,
                                              float* __restrict__ edge_e,
                                              int* __restrict__ counts) {
    const int g = threadIdx.x >> 4, sub = threadIdx.x & 15;
    const int e = blockIdx.x * 16 + g;      // grid sized exactly: E = 16 * 100000

    float4 rv = ((const float4*)review)[(size_t)e * 16 + sub];
    float4 vr = ((const float4*)v_re)[sub];
    float p = rv.x * vr.x + rv.y * vr.y + rv.z * vr.z + rv.w * vr.w;
    if (sub < MAX_R) p = fmaf(rating[(size_t)e * MAX_R + sub], v_ra[sub], p);

    p += __shfl_xor(p, 1);
    p += __shfl_xor(p, 2);
    p += __shfl_xor(p, 4);
    p += __shfl_xor(p, 8);

    if (sub == 0) {
        int s = edge[e], d = edge[N_EDGES + e];
        float sc = p + s_src[s] + s_dst[d];
        sc = sc > 0.f ? sc : ALPHA * sc;    // leaky_relu
        float ee = __expf(sc);
        edge_e[e] = ee;
        atomicAdd(&counts[s], 1);
    }
}

// ---------------- K3: exclusive scan of counts -> offsets (CSR row ptr) ----------------
__global__ __launch_bounds__(256) void k_scan1(const int* __restrict__ counts,
                                               int* __restrict__ offsets,
                                               int* __restrict__ bsums) {
    __shared__ int sh[256];
    int i = blockIdx.x * 256 + threadIdx.x;
    int v = (i < N_NODES) ? counts[i] : 0;
    sh[threadIdx.x] = v;
    __syncthreads();
    int incl = v;
#pragma unroll
    for (int d = 1; d < 256; d <<= 1) {
        int t = (threadIdx.x >= d) ? sh[threadIdx.x - d] : 0;
        __syncthreads();
        incl += t;
        sh[threadIdx.x] = incl;
        __syncthreads();
    }
    if (i < N_NODES) offsets[i] = incl - v;       // local exclusive
    if (threadIdx.x == 255) bsums[blockIdx.x] = incl;
}

__global__ __launch_bounds__(512) void k_scan2(int* __restrict__ bsums, int nb) {
    __shared__ int sh[512];
    int t = threadIdx.x;
    int v = (t < nb) ? bsums[t] : 0;
    sh[t] = v;
    __syncthreads();
    int incl = v;
#pragma unroll
    for (int d = 1; d < 512; d <<= 1) {
        int x = (t >= d) ? sh[t - d] : 0;
        __syncthreads();
        incl += x;
        sh[t] = incl;
        __syncthreads();
    }
    if (t < nb) bsums[t] = incl - v;              // exclusive block offsets
}

__global__ __launch_bounds__(256) void k_scan3(int* __restrict__ offsets,
                                               int* __restrict__ cursors,
                                               const int* __restrict__ bsums) {
    int i = blockIdx.x * 256 + threadIdx.x;
    if (i < N_NODES) {
        int v = offsets[i] + bsums[blockIdx.x];
        offsets[i] = v;
        cursors[i] = v;
    }
    if (i == 0) offsets[N_NODES] = N_EDGES;
}

// ---------------- K4: scatter edges into CSR order ----------------
__global__ __launch_bounds__(256) void k_scatter(const int* __restrict__ edge,
                                                 const float* __restrict__ edge_e,
                                                 int* __restrict__ cursors,
                                                 int* __restrict__ sdst,
                                                 float* __restrict__ see) {
    int e = blockIdx.x * 256 + threadIdx.x;       // grid exact: E = 6250*256
    int s = edge[e];
    int pos = atomicAdd(&cursors[s], 1);
    sdst[pos] = edge[N_EDGES + e];
    see[pos] = edge_e[e];
}

// ---------------- K5: per-node aggregate + finalize (elu) ----------------
// one wave per node, lane = column. rowsum folded into the same loop.
__global__ __launch_bounds__(256) void k_aggregate(const int* __restrict__ offsets,
                                                   const int* __restrict__ sdst,
                                                   const float* __restrict__ see,
                                                   const float* __restrict__ h,
                                                   float* __restrict__ out) {
    const int lane = threadIdx.x & 63;
    const int w = __builtin_amdgcn_readfirstlane(threadIdx.x >> 6);
    const int n = blockIdx.x * 4 + w;             // grid exact: 25000*4 = N
    int beg = offsets[n], end = offsets[n + 1];
    float acc = 0.f, rs = 1e-10f;
    for (int i = beg; i < end; ++i) {
        int d = sdst[i];
        float ee = see[i];
        rs += ee;
        acc = fmaf(ee, h[(size_t)d * OUT_F + lane], acc);
    }
    float hn = h[(size_t)n * OUT_F + lane];
    float v = acc / rs + hn;
    out[(size_t)n * OUT_F + lane] = v > 0.f ? v : expm1f(v);
}

extern "C" void kernel_launch(void* const* d_in, const int* in_sizes, int n_in,
                              void* d_out, int out_size, void* d_ws, size_t ws_size,
                              hipStream_t stream) {
    const float* inputs = (const float*)d_in[0];
    const int*   edge   = (const int*)d_in[1];
    const float* review = (const float*)d_in[2];
    const float* rating = (const float*)d_in[3];
    const float* W      = (const float*)d_in[4];
    const float* a      = (const float*)d_in[5];
    const float* re_W   = (const float*)d_in[6];
    const float* ra_W   = (const float*)d_in[7];
    float* out = (float*)d_out;

    char* ws = (char*)d_ws;
    size_t o = 0;
    auto alloc = [&](size_t bytes) -> void* {
        void* p = ws + o;
        o += (bytes + 255) & ~(size_t)255;
        return p;
    };
    float* h       = (float*)alloc((size_t)N_NODES * OUT_F * 4);   // 25.6 MB
    float* s_src   = (float*)alloc((size_t)N_NODES * 4);
    float* s_dst   = (float*)alloc((size_t)N_NODES * 4);
    float* v_re    = (float*)alloc(EMB * 4);
    float* v_ra    = (float*)alloc(8 * 4);
    float* edge_e  = (float*)alloc((size_t)N_EDGES * 4);           // 6.4 MB
    int*   counts  = (int*)alloc((size_t)(N_NODES + 1) * 4);
    int*   offsets = (int*)alloc((size_t)(N_NODES + 1) * 4);
    int*   cursors = (int*)alloc((size_t)(N_NODES + 1) * 4);
    int*   bsums   = (int*)alloc(512 * 4);
    int*   sdst    = (int*)alloc((size_t)N_EDGES * 4);             // 6.4 MB
    float* see     = (float*)alloc((size_t)N_EDGES * 4);           // 6.4 MB

    hipMemsetAsync(counts, 0, (size_t)N_NODES * 4, stream);

    k_gemm<<<N_NODES / 4, 256, 0, stream>>>(inputs, W, a, h, s_src, s_dst);
    k_vre<<<1, 128, 0, stream>>>(re_W, ra_W, a, v_re, v_ra);
    k_edge<<<N_EDGES / 16, 256, 0, stream>>>(edge, review, rating, s_src, s_dst,
                                             v_re, v_ra, edge_e, counts);
    int nb1 = (N_NODES + 255) / 256;   // 391
    k_scan1<<<nb1, 256, 0, stream>>>(counts, offsets, bsums);
    k_scan2<<<1, 512, 0, stream>>>(bsums, nb1);
    k_scan3<<<nb1, 256, 0, stream>>>(offsets, cursors, bsums);
    k_scatter<<<N_EDGES / 256, 256, 0, stream>>>(edge, edge_e, cursors, sdst, see);
    k_aggregate<<<N_NODES / 4, 256, 0, stream>>>(offsets, sdst, see, h, out);
}

// Round 4
// 892.052 us; speedup vs baseline: 1.0686x; 1.0686x over previous
//
#include <hip/hip_runtime.h>
#include <hip/hip_bf16.h>

#define N_NODES 100000
#define N_EDGES 1600000
#define IN_F 128
#define OUT_F 64
#define EMB 64
#define ATT 32
#define MAX_R 5
#define ALPHA 0.2f

#define GEMM_RPW 10                               // rows per wave
#define GEMM_BLOCKS (N_NODES / (4 * GEMM_RPW))    // 2500, exact

// ---------------- K1: h = inputs @ W  (+ s_src, s_dst epilogue) ----------------
// Each lane register-caches its W column (128 VGPRs). Input rows are read via
// wave-uniform addresses (scalar pipe) -> zero LDS traffic, VALU-bound.
__global__ __launch_bounds__(256) void k_gemm(const float* __restrict__ inp,
                                              const float* __restrict__ W,
                                              const float* __restrict__ a,
                                              float* __restrict__ h,
                                              float* __restrict__ s_src,
                                              float* __restrict__ s_dst) {
    const int lane = threadIdx.x & 63;
    const int wu = __builtin_amdgcn_readfirstlane(threadIdx.x >> 6);

    float Wreg[IN_F];                   // Wreg[k] = W[k][lane], coalesced 256B/load
#pragma unroll
    for (int k = 0; k < IN_F; ++k)
        Wreg[k] = W[k * OUT_F + lane];

    const float asrc = a[lane], adst = a[OUT_F + lane];
    const int r0 = (blockIdx.x * 4 + wu) * GEMM_RPW;

    for (int j = 0; j < GEMM_RPW; ++j) {
        const int r = r0 + j;
        const float* __restrict__ row = inp + (size_t)r * IN_F;  // wave-uniform
        float acc = 0.f;
#pragma unroll
        for (int k = 0; k < IN_F; ++k)
            acc = fmaf(row[k], Wreg[k], acc);    // s_load x v_fma

        h[(size_t)r * OUT_F + lane] = acc;

        float ps = acc * asrc, pd = acc * adst;
#pragma unroll
        for (int m = 32; m; m >>= 1) {
            ps += __shfl_xor(ps, m);
            pd += __shfl_xor(pd, m);
        }
        if (lane == 0) { s_src[r] = ps; s_dst[r] = pd; }
    }
}

// ---------------- K1b: v_re = re_W @ a_re (64), v_ra = ra_W @ a_ra (5) ----------------
__global__ void k_vre(const float* __restrict__ re_W, const float* __restrict__ ra_W,
                      const float* __restrict__ a, float* __restrict__ v_re,
                      float* __restrict__ v_ra) {
    int t = threadIdx.x;
    if (t < EMB) {
        float s = 0.f;
        for (int j = 0; j < ATT; ++j) s = fmaf(re_W[t * ATT + j], a[2 * OUT_F + j], s);
        v_re[t] = s;
    } else if (t < EMB + MAX_R) {
        int m = t - EMB;
        float s = 0.f;
        for (int j = 0; j < ATT; ++j) s = fmaf(ra_W[m * ATT + j], a[2 * OUT_F + ATT + j], s);
        v_ra[m] = s;
    }
}

// ---------------- K2: histogram of src ----------------
__global__ __launch_bounds__(256) void k_count(const int* __restrict__ edge,
                                               int* __restrict__ counts) {
    int e = blockIdx.x * 256 + threadIdx.x;       // grid exact: 6250*256 = E
    atomicAdd(&counts[edge[e]], 1);
}

// ---------------- K3: exclusive scan of counts -> offsets (CSR row ptr) ----------------
__global__ __launch_bounds__(256) void k_scan1(const int* __restrict__ counts,
                                               int* __restrict__ offsets,
                                               int* __restrict__ bsums) {
    __shared__ int sh[256];
    int i = blockIdx.x * 256 + threadIdx.x;
    int v = (i < N_NODES) ? counts[i] : 0;
    sh[threadIdx.x] = v;
    __syncthreads();
    int incl = v;
#pragma unroll
    for (int d = 1; d < 256; d <<= 1) {
        int t = (threadIdx.x >= d) ? sh[threadIdx.x - d] : 0;
        __syncthreads();
        incl += t;
        sh[threadIdx.x] = incl;
        __syncthreads();
    }
    if (i < N_NODES) offsets[i] = incl - v;       // local exclusive
    if (threadIdx.x == 255) bsums[blockIdx.x] = incl;
}

__global__ __launch_bounds__(512) void k_scan2(int* __restrict__ bsums, int nb) {
    __shared__ int sh[512];
    int t = threadIdx.x;
    int v = (t < nb) ? bsums[t] : 0;
    sh[t] = v;
    __syncthreads();
    int incl = v;
#pragma unroll
    for (int d = 1; d < 512; d <<= 1) {
        int x = (t >= d) ? sh[t - d] : 0;
        __syncthreads();
        incl += x;
        sh[t] = incl;
        __syncthreads();
    }
    if (t < nb) bsums[t] = incl - v;              // exclusive block offsets
}

__global__ __launch_bounds__(256) void k_scan3(int* __restrict__ offsets,
                                               int* __restrict__ cursors,
                                               const int* __restrict__ bsums) {
    int i = blockIdx.x * 256 + threadIdx.x;
    if (i < N_NODES) {
        int v = offsets[i] + bsums[blockIdx.x];
        offsets[i] = v;
        cursors[i] = v;
    }
    if (i == 0) offsets[N_NODES] = N_EDGES;
}

// ---------------- K4: per-edge score + direct CSR scatter of (dst, ee) ----------------
// 16 lanes per edge; review row (64 floats) read as 16 x float4, fully coalesced.
__global__ __launch_bounds__(256) void k_edge(const int* __restrict__ edge,
                                              const float* __restrict__ review,
                                              const float* __restrict__ rating,
                                              const float* __restrict__ s_src,
                                              const float* __restrict__ s_dst,
                                              const float* __restrict__ v_re,
                                              const float* __restrict__ v_ra,
                                              int* __restrict__ cursors,
                                              int2* __restrict__ packed) {
    const int g = threadIdx.x >> 4, sub = threadIdx.x & 15;
    const int e = blockIdx.x * 16 + g;            // grid exact: E = 16 * 100000

    float4 rv = ((const float4*)review)[(size_t)e * 16 + sub];
    float4 vr = ((const float4*)v_re)[sub];
    float p = rv.x * vr.x + rv.y * vr.y + rv.z * vr.z + rv.w * vr.w;
    if (sub < MAX_R) p = fmaf(rating[(size_t)e * MAX_R + sub], v_ra[sub], p);

    p += __shfl_xor(p, 1);
    p += __shfl_xor(p, 2);
    p += __shfl_xor(p, 4);
    p += __shfl_xor(p, 8);

    if (sub == 0) {
        int s = edge[e], d = edge[N_EDGES + e];
        float sc = p + s_src[s] + s_dst[d];
        sc = sc > 0.f ? sc : ALPHA * sc;          // leaky_relu
        float ee = __expf(sc);
        int pos = atomicAdd(&cursors[s], 1);
        packed[pos] = make_int2(d, __float_as_int(ee));
    }
}

// ---------------- K5: per-node aggregate + finalize (elu) ----------------
// one wave per node, lane = column. rowsum folded in; 2-edge unroll for MLP.
__global__ __launch_bounds__(256) void k_aggregate(const int* __restrict__ offsets,
                                                   const int2* __restrict__ packed,
                                                   const float* __restrict__ h,
                                                   float* __restrict__ out) {
    const int lane = threadIdx.x & 63;
    const int wu = __builtin_amdgcn_readfirstlane(threadIdx.x >> 6);
    const int n = blockIdx.x * 4 + wu;            // grid exact: 25000*4 = N
    int beg = offsets[n], end = offsets[n + 1];
    float acc = 0.f, rs = 1e-10f;
    int i = beg;
    for (; i + 2 <= end; i += 2) {
        int2 p0 = packed[i], p1 = packed[i + 1];  // wave-uniform -> scalar loads
        float e0 = __int_as_float(p0.y), e1 = __int_as_float(p1.y);
        float h0 = h[(size_t)p0.x * OUT_F + lane];
        float h1 = h[(size_t)p1.x * OUT_F + lane];
        rs += e0 + e1;
        acc = fmaf(e0, h0, fmaf(e1, h1, acc));
    }
    if (i < end) {
        int2 p0 = packed[i];
        float e0 = __int_as_float(p0.y);
        rs += e0;
        acc = fmaf(e0, h[(size_t)p0.x * OUT_F + lane], acc);
    }
    float hn = h[(size_t)n * OUT_F + lane];
    float v = acc / rs + hn;
    out[(size_t)n * OUT_F + lane] = v > 0.f ? v : expm1f(v);
}

extern "C" void kernel_launch(void* const* d_in, const int* in_sizes, int n_in,
                              void* d_out, int out_size, void* d_ws, size_t ws_size,
                              hipStream_t stream) {
    const float* inputs = (const float*)d_in[0];
    const int*   edge   = (const int*)d_in[1];
    const float* review = (const float*)d_in[2];
    const float* rating = (const float*)d_in[3];
    const float* W      = (const float*)d_in[4];
    const float* a      = (const float*)d_in[5];
    const float* re_W   = (const float*)d_in[6];
    const float* ra_W   = (const float*)d_in[7];
    float* out = (float*)d_out;

    char* ws = (char*)d_ws;
    size_t o = 0;
    auto alloc = [&](size_t bytes) -> void* {
        void* p = ws + o;
        o += (bytes + 255) & ~(size_t)255;
        return p;
    };
    float* h       = (float*)alloc((size_t)N_NODES * OUT_F * 4);   // 25.6 MB
    float* s_src   = (float*)alloc((size_t)N_NODES * 4);
    float* s_dst   = (float*)alloc((size_t)N_NODES * 4);
    float* v_re    = (float*)alloc(EMB * 4);
    float* v_ra    = (float*)alloc(8 * 4);
    int*   counts  = (int*)alloc((size_t)(N_NODES + 1) * 4);
    int*   offsets = (int*)alloc((size_t)(N_NODES + 1) * 4);
    int*   cursors = (int*)alloc((size_t)(N_NODES + 1) * 4);
    int*   bsums   = (int*)alloc(512 * 4);
    int2*  packed  = (int2*)alloc((size_t)N_EDGES * 8);            // 12.8 MB

    hipMemsetAsync(counts, 0, (size_t)N_NODES * 4, stream);

    k_gemm<<<GEMM_BLOCKS, 256, 0, stream>>>(inputs, W, a, h, s_src, s_dst);
    k_vre<<<1, 128, 0, stream>>>(re_W, ra_W, a, v_re, v_ra);
    k_count<<<N_EDGES / 256, 256, 0, stream>>>(edge, counts);
    int nb1 = (N_NODES + 255) / 256;   // 391
    k_scan1<<<nb1, 256, 0, stream>>>(counts, offsets, bsums);
    k_scan2<<<1, 512, 0, stream>>>(bsums, nb1);
    k_scan3<<<nb1, 256, 0, stream>>>(offsets, cursors, bsums);
    k_edge<<<N_EDGES / 16, 256, 0, stream>>>(edge, review, rating, s_src, s_dst,
                                             v_re, v_ra, cursors, packed);
    k_aggregate<<<N_NODES / 4, 256, 0, stream>>>(offsets, packed, h, out);
}